// Round 1
// baseline (898.836 us; speedup 1.0000x reference)
//
#include <hip/hip_runtime.h>

// Problem constants (from reference):
// x: [B=2, C=16, D1=8, D2=8, D3=64, D4=64] fp32
// w: [O=32, I=16, 3,3,3,3] fp32
// out = relu(conv4d_valid(x, w)): [2, 32, 6, 6, 62, 62] fp32
#define BB 2
#define CI 16
#define CO 32
#define D1 8
#define D2 8
#define D3 64
#define D4 64
#define E1 6
#define E2 6
#define E3 62
#define E4 62

// spatial size per output channel
#define OSP (E1 * E2 * E3 * E4)  // 138384
#define TOTAL (BB * OSP)         // 276768 output pixels

__global__ __launch_bounds__(256) void conv4d_relu_kernel(
    const float* __restrict__ x, const float* __restrict__ w,
    float* __restrict__ out) {
  int p = blockIdx.x * 256 + threadIdx.x;
  if (p >= TOTAL) return;

  // p -> (b, e1, e2, e3, e4)
  int e4 = p % E4;
  int t = p / E4;
  int e3 = t % E3;
  t /= E3;
  int e2 = t % E2;
  t /= E2;
  int e1 = t % E1;
  int b = t / E1;

  float acc[CO];
#pragma unroll
  for (int o = 0; o < CO; ++o) acc[o] = 0.f;

  // Loop over (c, k1, k2) stages; k1,k2,c kept as runtime loops to bound
  // code size (~300 instrs/stage, 93% FMA density). Weight addresses depend
  // only on loop counters -> block-uniform -> scalar loads.
  for (int c = 0; c < CI; ++c) {
    for (int k1 = 0; k1 < 3; ++k1) {
      for (int k2 = 0; k2 < 3; ++k2) {
        const float* xb =
            x + (((((size_t)b * CI + c) * D1 + (e1 + k1)) * D2 + (e2 + k2)) *
                     D3 + e3) * D4 + e4;
        float in[9];
#pragma unroll
        for (int k3 = 0; k3 < 3; ++k3)
#pragma unroll
          for (int k4 = 0; k4 < 3; ++k4)
            in[k3 * 3 + k4] = xb[(size_t)k3 * D4 + k4];

        // w flat index: o*1296 + c*81 + k1*27 + k2*9 + k3*3 + k4
        const float* wb = w + (size_t)c * 81 + k1 * 27 + k2 * 9;
#pragma unroll
        for (int o = 0; o < CO; ++o) {
          const float* wo = wb + (size_t)o * (CI * 81);
#pragma unroll
          for (int t9 = 0; t9 < 9; ++t9)
            acc[o] = fmaf(in[t9], wo[t9], acc[o]);
        }
      }
    }
  }

  // out[b, o, e1, e2, e3, e4]
  size_t spatial = (((size_t)e1 * E2 + e2) * E3 + e3) * (size_t)E4 + e4;
  size_t base = (size_t)b * CO * OSP + spatial;
#pragma unroll
  for (int o = 0; o < CO; ++o)
    out[base + (size_t)o * OSP] = fmaxf(acc[o], 0.f);
}

extern "C" void kernel_launch(void* const* d_in, const int* in_sizes, int n_in,
                              void* d_out, int out_size, void* d_ws,
                              size_t ws_size, hipStream_t stream) {
  const float* x = (const float*)d_in[0];
  const float* w = (const float*)d_in[1];
  float* out = (float*)d_out;
  int nblk = (TOTAL + 255) / 256;  // 1082
  conv4d_relu_kernel<<<dim3(nblk), dim3(256), 0, stream>>>(x, w, out);
}

// Round 2
// 154.284 us; speedup vs baseline: 5.8259x; 5.8259x over previous
//
#include <hip/hip_runtime.h>

// x: [B=2, C=16, D1=8, D2=8, D3=64, D4=64] fp32
// w: [O=32, I=16, 3,3,3,3] fp32
// out = relu(conv4d_valid(x, w)): [2, 32, 6, 6, 62, 62] fp32
//
// MFMA mapping per tap (k1,k2,k3,k4): D[32 pix][32 o] += A[32 pix][16 c] * B[16 c][32 o]
// via v_mfma_f32_32x32x16_bf16. 81 taps accumulate in fp32.

typedef __attribute__((ext_vector_type(8))) __bf16 bf16x8;
typedef __attribute__((ext_vector_type(16))) float f32x16;

#define CSTRIDE 262144  // 8*8*64*64 elements, channel stride in x

// ---- weight prep: w[o][c][t81] fp32 -> wT[t81][o32][c16] bf16 (83 KB in d_ws)
__global__ __launch_bounds__(256) void prep_w(const float* __restrict__ w,
                                              __bf16* __restrict__ wT) {
  int n = blockIdx.x * 256 + threadIdx.x;
  if (n >= 41472) return;
  int c = n & 15;
  int o = (n >> 4) & 31;
  int t = n >> 9;
  wT[t * 512 + o * 16 + c] = (__bf16)w[(o * 16 + c) * 81 + t];
}

__global__ __launch_bounds__(256, 3) void conv_mfma(
    const float* __restrict__ x, const __bf16* __restrict__ wT,
    float* __restrict__ out) {
  int bid = blockIdx.x;
  int c3 = bid % 11;
  int t = bid / 11;
  int e2 = t % 6;
  t /= 6;
  int e1 = t % 6;
  int b = t / 6;
  int r0 = c3 * 6;                     // e3 chunk start
  int T3 = (62 - r0 < 6) ? (62 - r0) : 6;  // rows this chunk (6 or 2)
  int Ract = T3 + 2;                   // staged d3 rows
  int lane = threadIdx.x & 63;
  int wave = threadIdx.x >> 6;
  int m32 = lane & 31;
  int half = lane >> 5;

  // [k2][d3row][c-half][d4col(+2 halo for k4 overread)][c8]
  __shared__ __align__(16) __bf16 xs[3][8][2][66][8];

  int ntiles = (T3 == 6) ? 3 : 1;  // M-tiles per wave (tile = 32 e4 cols x 1 e3 row)
  f32x16 acc[3];
#pragma unroll
  for (int i = 0; i < 3; ++i)
#pragma unroll
    for (int r = 0; r < 16; ++r) acc[i][r] = 0.f;

  for (int k1 = 0; k1 < 3; ++k1) {
    if (k1) __syncthreads();
    // ---- stage: x[b, :, e1+k1, e2+k2, r0+row, col] -> xs (bf16, channel-last)
    int nunits = 3 * Ract * 128;  // (k2, row, chalf, col) units
    for (int u = threadIdx.x; u < nunits; u += 256) {
      int col = u & 63;
      int ch = (u >> 6) & 1;
      int rw = (u >> 7) % Ract;
      int k2 = (u >> 7) / Ract;
      const float* g = x +
          ((((size_t)(b * 16 + ch * 8) * 8 + (e1 + k1)) * 8 + (e2 + k2)) * 64 +
           (r0 + rw)) * 64 + col;
      bf16x8 v;
#pragma unroll
      for (int i = 0; i < 8; ++i) v[i] = (__bf16)g[(size_t)i * CSTRIDE];
      *(bf16x8*)&xs[k2][rw][ch][col][0] = v;  // one ds_write_b128, conflict-free
    }
    __syncthreads();
    // ---- compute: 27 taps (k2,k3,k4) x ntiles MFMAs
    const __bf16* wbase = wT + (size_t)k1 * 27 * 512 + m32 * 16 + half * 8;
    for (int k2 = 0; k2 < 3; ++k2) {
#pragma unroll
      for (int k3 = 0; k3 < 3; ++k3) {
#pragma unroll
        for (int k4 = 0; k4 < 3; ++k4) {
          bf16x8 bf = *(const bf16x8*)(wbase + ((k2 * 3 + k3) * 3 + k4) * 512);
#pragma unroll
          for (int i = 0; i < 3; ++i) {
            if (i >= ntiles) break;
            int tile = wave + 4 * i;
            int tr = tile >> 1;   // e3 row within chunk
            int th = tile & 1;    // e4 half (cols 0-31 / 32-63)
            bf16x8 af = *(const bf16x8*)
                &xs[k2][tr + k3][half][th * 32 + m32 + k4][0];
            acc[i] = __builtin_amdgcn_mfma_f32_32x32x16_bf16(af, bf, acc[i],
                                                             0, 0, 0);
          }
        }
      }
    }
  }
  __syncthreads();  // xs reuse as epilogue scratch

  // ---- epilogue: per-wave LDS transpose (stride 33 = conflict-free), ReLU, store
  float* sc = (float*)&xs[0][0][0][0][0] + wave * 1056;  // 32*33 floats per wave
#pragma unroll
  for (int i = 0; i < 3; ++i) {
    if (i >= ntiles) break;
    int tile = wave + 4 * i;
    int tr = tile >> 1;
    int th = tile & 1;
#pragma unroll
    for (int r = 0; r < 16; ++r) {
      int m = (r & 3) + 8 * (r >> 2) + 4 * half;  // pixel row in tile
      sc[m * 33 + m32] = acc[i][r];               // [pix][o]
    }
    int e3 = r0 + tr;
    size_t obase = ((((size_t)b * 32) * 6 + e1) * 6 + e2) * 3844 +
                   (size_t)e3 * 62;
#pragma unroll
    for (int it = 0; it < 16; ++it) {
      int o = it * 2 + half;
      float v = sc[m32 * 33 + o];
      v = fmaxf(v, 0.f);
      int e4 = th * 32 + m32;
      if (e4 < 62) out[obase + (size_t)o * 138384 + e4] = v;
    }
  }
}

extern "C" void kernel_launch(void* const* d_in, const int* in_sizes, int n_in,
                              void* d_out, int out_size, void* d_ws,
                              size_t ws_size, hipStream_t stream) {
  const float* x = (const float*)d_in[0];
  const float* w = (const float*)d_in[1];
  float* out = (float*)d_out;
  __bf16* wT = (__bf16*)d_ws;  // 41472 bf16 = 83 KB
  prep_w<<<dim3(162), dim3(256), 0, stream>>>(w, wT);
  conv_mfma<<<dim3(792), dim3(256), 0, stream>>>(x, wT, out);
}

// Round 3
// 116.498 us; speedup vs baseline: 7.7155x; 1.3243x over previous
//
#include <hip/hip_runtime.h>

// x: [B=2, C=16, D1=8, D2=8, D3=64, D4=64] fp32
// w: [O=32, I=16, 3,3,3,3] fp32
// out = relu(conv4d_valid(x, w)): [2, 32, 6, 6, 62, 62] fp32
//
// Dataflow: per tap, D[32 pix][32 o] += A[32 pix][16 c] * B[16 c][32 o]
// (v_mfma_f32_32x32x16_bf16, fp32 acc, 81 taps).
// prep: x -> xb bf16 channel-last [b][d1][d2][d3][ch2][col64][c8] so conv
// staging is contiguous global_load_lds(16B) and A-frags are conflict-free
// ds_read_b128 at constant offsets.

typedef __attribute__((ext_vector_type(8))) __bf16 bf16x8;
typedef __attribute__((ext_vector_type(16))) float f32x16;

#define CSTRIDE 262144  // x channel stride, elements

#define WT_OFF 0        // 41472 bf16 = 83 KB
#define XB_OFF 131072   // 8192 rows * 2048 B = 16.78 MB
#define BUF_STRIDE 12544  // 6 rows * 2 KB staged + 256 B pad (halo overread)

typedef __attribute__((address_space(1))) const unsigned int gu32;
typedef __attribute__((address_space(3))) unsigned int lu32;

__device__ __forceinline__ void async_cp16(const void* g, void* l) {
  // LDS dest = wave-uniform base + lane*16 (HW rule); pass uniform base.
  __builtin_amdgcn_global_load_lds((gu32*)g, (lu32*)l, 16, 0, 0);
}

// ---- prep: blocks 0..511 transform x -> xb; blocks 512..543 build wT[t][o][c]
__global__ __launch_bounds__(256) void prep(const float* __restrict__ x,
                                            const float* __restrict__ w,
                                            unsigned char* __restrict__ ws) {
  int blk = blockIdx.x;
  if (blk < 512) {
    __bf16* xb = (__bf16*)(ws + XB_OFF);
    int n = blk * 256 + threadIdx.x;  // (b,d1,d2,d3,colgroup4)
    int cg = n & 15;
    int d3 = (n >> 4) & 63;
    int d2 = (n >> 10) & 7;
    int d1 = (n >> 13) & 7;
    int b = n >> 16;
    const float* gx =
        x + ((((b * 16) * 8 + d1) * 8 + d2) * 64 + d3) * 64 + cg * 4;
    float4 v[16];
#pragma unroll
    for (int c = 0; c < 16; ++c) v[c] = *(const float4*)(gx + (size_t)c * CSTRIDE);
    __bf16* row = xb + ((((b * 8 + d1) * 8 + d2) * 64 + d3) * 1024);
#pragma unroll
    for (int ch = 0; ch < 2; ++ch) {
#pragma unroll
      for (int j = 0; j < 4; ++j) {
        bf16x8 o;
#pragma unroll
        for (int cc = 0; cc < 8; ++cc)
          o[cc] = (__bf16)(((const float*)&v[ch * 8 + cc])[j]);
        *(bf16x8*)(row + ch * 512 + (cg * 4 + j) * 8) = o;
      }
    }
  } else {
    int o = blk - 512;  // one output channel per block
    __bf16* wT = (__bf16*)(ws + WT_OFF);
#pragma unroll
    for (int base = 0; base < 1296; base += 256) {
      int idx = base + threadIdx.x;
      if (idx < 1296) {
        int c = idx / 81, t = idx % 81;
        wT[t * 512 + o * 16 + c] = (__bf16)w[o * 1296 + idx];
      }
    }
  }
}

__global__ __launch_bounds__(256, 4) void conv_mfma(
    const unsigned char* __restrict__ ws, float* __restrict__ out) {
  const __bf16* wT = (const __bf16*)(ws + WT_OFF);
  const unsigned char* xb = ws + XB_OFF;

  int bid = blockIdx.x;
  int c3 = bid & 15;  // e3 chunk of 4 (last chunk: 2)
  int t = bid >> 4;
  int e2 = t % 6;
  t /= 6;
  int e1 = t % 6;
  int b = t / 6;
  int r0 = c3 * 4;
  int T3 = (c3 == 15) ? 2 : 4;
  int nchunk = (T3 + 2) * 2;  // staged 1 KB chunks (rows+halo)
  int ntiles = T3 >> 1;       // M-tiles per wave: 2 or 1

  int lane = threadIdx.x & 63;
  int wave = threadIdx.x >> 6;
  int m32 = lane & 31;
  int half = lane >> 5;

  __shared__ __align__(16) unsigned char lds[2 * BUF_STRIDE];

  // per-lane A-frag base: tile0 = wave -> (tr=wave>>1, th=wave&1)
  int ab_off = (wave >> 1) * 2048 + half * 1024 + ((wave & 1) * 32 + m32) * 16;

  f32x16 acc[2];
#pragma unroll
  for (int i = 0; i < 2; ++i)
#pragma unroll
    for (int r = 0; r < 16; ++r) acc[i][r] = 0.f;

  // prologue: stage phase 0 (k1=0,k2=0) into buf 0
  {
    const unsigned char* g =
        xb + (((b * 8 + e1) * 8 + e2) * 64 + r0) * 2048;
#pragma unroll
    for (int j = 0; j < 3; ++j) {
      int ck = j * 4 + wave;
      if (ck < nchunk) async_cp16(g + ck * 1024 + lane * 16, lds + ck * 1024);
    }
  }

  for (int p = 0; p < 9; ++p) {  // phase = (k1,k2)
    __syncthreads();  // drains stage(p) vmcnt; fences buf[(p+1)&1] reuse
    // B-frags first (so their vmcnt waits don't drain the stage below)
    const __bf16* wp = wT + p * 4608 + m32 * 16 + half * 8;
    bf16x8 bfr[9];
#pragma unroll
    for (int t9 = 0; t9 < 9; ++t9) bfr[t9] = *(const bf16x8*)(wp + t9 * 512);
    // stage phase p+1 into the other buffer; in flight during compute(p)
    if (p < 8) {
      int np = p + 1;
      int nk1 = np / 3, nk2 = np - nk1 * 3;
      const unsigned char* g =
          xb + (((b * 8 + e1 + nk1) * 8 + e2 + nk2) * 64 + r0) * 2048;
      unsigned char* dst = lds + (np & 1) * BUF_STRIDE;
#pragma unroll
      for (int j = 0; j < 3; ++j) {
        int ck = j * 4 + wave;
        if (ck < nchunk)
          async_cp16(g + ck * 1024 + lane * 16, dst + ck * 1024);
      }
    }
    // compute: 9 taps x ntiles, constant ds offsets, zero addr VALU
    const unsigned char* abase = lds + (p & 1) * BUF_STRIDE + ab_off;
#pragma unroll
    for (int k3 = 0; k3 < 3; ++k3) {
#pragma unroll
      for (int k4 = 0; k4 < 3; ++k4) {
        bf16x8 bf = bfr[k3 * 3 + k4];
        bf16x8 a0 = *(const bf16x8*)(abase + k3 * 2048 + k4 * 16);
        acc[0] =
            __builtin_amdgcn_mfma_f32_32x32x16_bf16(a0, bf, acc[0], 0, 0, 0);
        if (ntiles == 2) {
          bf16x8 a1 = *(const bf16x8*)(abase + 4096 + k3 * 2048 + k4 * 16);
          acc[1] =
              __builtin_amdgcn_mfma_f32_32x32x16_bf16(a1, bf, acc[1], 0, 0, 0);
        }
      }
    }
  }
  __syncthreads();

  // epilogue: per-wave LDS transpose (stride 33), ReLU, coalesced store
  float* scw = (float*)(void*)lds + wave * 1056;
#pragma unroll
  for (int i = 0; i < 2; ++i) {
    if (i >= ntiles) break;
    int tr = (wave >> 1) + 2 * i;
    int th = wave & 1;
#pragma unroll
    for (int r = 0; r < 16; ++r) {
      int m = (r & 3) + 8 * (r >> 2) + 4 * half;  // pixel row in tile
      scw[m * 33 + m32] = acc[i][r];              // [pix][o]
    }
    int e3 = r0 + tr;
    size_t obase =
        ((((size_t)b * 32) * 6 + e1) * 6 + e2) * 3844 + (size_t)e3 * 62;
    int e4 = th * 32 + m32;
#pragma unroll
    for (int it = 0; it < 16; ++it) {
      int o = it * 2 + half;
      float v = fmaxf(scw[m32 * 33 + o], 0.f);
      if (e4 < 62) out[obase + (size_t)o * 138384 + e4] = v;
    }
  }
}

extern "C" void kernel_launch(void* const* d_in, const int* in_sizes, int n_in,
                              void* d_out, int out_size, void* d_ws,
                              size_t ws_size, hipStream_t stream) {
  const float* x = (const float*)d_in[0];
  const float* w = (const float*)d_in[1];
  float* out = (float*)d_out;
  unsigned char* ws = (unsigned char*)d_ws;
  prep<<<dim3(544), dim3(256), 0, stream>>>(x, w, ws);
  conv_mfma<<<dim3(1152), dim3(256), 0, stream>>>(ws, out);
}